// Round 5
// baseline (461.910 us; speedup 1.0000x reference)
//
#include <hip/hip_runtime.h>
#include <hip/hip_bf16.h>

#define BT 16384   // B*T = 32*512
#define DIM 768
#define NH 12
#define DFF 3072

typedef __attribute__((ext_vector_type(8))) short short8;
typedef __attribute__((ext_vector_type(4))) float floatx4;
typedef __attribute__((ext_vector_type(4))) unsigned short ushort4b;

using bf16 = __hip_bfloat16;

static __device__ __forceinline__ float b2f(bf16 v) { return __bfloat162float(v); }
static __device__ __forceinline__ bf16 f2b(float v) { return __float2bfloat16(v); }

// async global->LDS DMA, 16B per lane; LDS dest is wave-uniform base + lane*16
static __device__ __forceinline__ void gload_lds16(const void* g, void* l) {
    __builtin_amdgcn_global_load_lds(
        (const __attribute__((address_space(1))) unsigned int*)g,
        (__attribute__((address_space(3))) unsigned int*)l, 16, 0, 0);
}

// ---- small pack: wqkv [256][768] (rows>=216 zero), wo_t [768][96] (k>=72 zero) ----
__global__ __launch_bounds__(256) void pack_small_kernel(
    const float* __restrict__ Wq, const float* __restrict__ Wk, const float* __restrict__ Wv,
    const float* __restrict__ Wo, bf16* __restrict__ wqkv, bf16* __restrict__ wo_t)
{
    int i = blockIdx.x * 256 + threadIdx.x;
    const int S0 = 256 * 768, S1 = 768 * 96;
    if (i < S0) {
        int c = i / 768, dd = i % 768;
        float v = 0.f;
        if (c < 216) {
            int sel = c / 72, cc = c % 72, h = cc / 6, e = cc % 6;
            const float* W = (sel == 0) ? Wq : (sel == 1) ? Wk : Wv;   // (H, D, E)
            v = W[((size_t)h * 768 + dd) * 6 + e];
        }
        wqkv[i] = f2b(v);
    } else if ((i -= S0) < S1) {
        int n = i / 96, r = i % 96;              // Wo is (72, 768): [r][n]
        wo_t[i] = f2b(r < 72 ? Wo[r * 768 + n] : 0.f);
    }
}

// ---- tiled transpose: in fp32 [R][C] -> out bf16 [C][R]; grid (C/32, R/32), 256 thr ----
__global__ __launch_bounds__(256) void transpose_kernel(
    const float* __restrict__ in, bf16* __restrict__ out, int R, int C)
{
    __shared__ float t[32][33];
    int c0 = blockIdx.x * 32, r0 = blockIdx.y * 32;
    int cx = threadIdx.x & 31, ry = threadIdx.x >> 5;   // ry 0..7
#pragma unroll
    for (int j = 0; j < 4; j++)
        t[ry + j * 8][cx] = in[(size_t)(r0 + ry + j * 8) * C + c0 + cx];
    __syncthreads();
    int rx = cx, cy = ry;
#pragma unroll
    for (int j = 0; j < 4; j++)
        out[(size_t)(c0 + cy + j * 8) * R + r0 + rx] = f2b(t[rx][cy + j * 8]);
}

// ---------------- LayerNorm: 192 threads, float4 loads, 8B packed bf16 stores ----------------
__global__ __launch_bounds__(192) void ln_kernel(
    const float* __restrict__ x, const float* __restrict__ g, const float* __restrict__ be,
    bf16* __restrict__ out)
{
    int row = blockIdx.x;
    int tid = threadIdx.x;
    const float4* xr = (const float4*)(x + (size_t)row * DIM);
    float4 v = xr[tid];
    float s = v.x + v.y + v.z + v.w;
    float s2 = v.x * v.x + v.y * v.y + v.z * v.z + v.w * v.w;
#pragma unroll
    for (int off = 32; off; off >>= 1) {
        s += __shfl_down(s, off);
        s2 += __shfl_down(s2, off);
    }
    __shared__ float red[6];
    int wv = tid >> 6, ln = tid & 63;
    if (ln == 0) { red[wv] = s; red[3 + wv] = s2; }
    __syncthreads();
    float ts = red[0] + red[1] + red[2];
    float ts2 = red[3] + red[4] + red[5];
    float mean = ts * (1.f / 768.f);
    float var = ts2 * (1.f / 768.f) - mean * mean;
    float rstd = rsqrtf(var + 1e-5f);
    int c = tid * 4;
    float o0 = (v.x - mean) * rstd * g[c + 0] + be[c + 0];
    float o1 = (v.y - mean) * rstd * g[c + 1] + be[c + 1];
    float o2 = (v.z - mean) * rstd * g[c + 2] + be[c + 2];
    float o3 = (v.w - mean) * rstd * g[c + 3] + be[c + 3];
    bf16 h0 = f2b(o0), h1 = f2b(o1), h2 = f2b(o2), h3 = f2b(o3);
    ushort4b pk;
    pk[0] = *(unsigned short*)&h0; pk[1] = *(unsigned short*)&h1;
    pk[2] = *(unsigned short*)&h2; pk[3] = *(unsigned short*)&h3;
    *(ushort4b*)(out + (size_t)row * DIM + c) = pk;
}

// ---------------- 128x128-tile MFMA GEMM (QKV / WO): static N,K ----------------
template <int N, int K, int NSLAB, bool RELU, bool BIAS, bool RES, bool BF16OUT>
__global__ __launch_bounds__(256) void gemm_kernel(
    const bf16* __restrict__ A, const bf16* __restrict__ Bt,
    const float* __restrict__ bias, const float* __restrict__ res,
    void* __restrict__ Cv, int M)
{
    constexpr int STAGE = NSLAB * 2 * 128 * 32 * 2;
    constexpr int SMEM_BYTES = BF16OUT ? (STAGE > 128 * 136 * 2 ? STAGE : 128 * 136 * 2) : STAGE;
    __shared__ __align__(16) char smem[SMEM_BYTES];
    bf16* lA = (bf16*)smem;                       // [NSLAB][128][32]
    bf16* lB = lA + NSLAB * 128 * 32;

    const int tid = threadIdx.x;
    const int bm = blockIdx.x * 128;
    const int bn = blockIdx.y * 128;
    const int wave = tid >> 6, lane = tid & 63;
    const int wm = (wave >> 1) * 64, wn = (wave & 1) * 64;
    const int quad = lane >> 4, l16 = lane & 15;
    const int lrow = lane >> 2;
    const int lkc = (lane & 3) * 8;

    floatx4 acc[4][4] = {};

    for (int k0 = 0; k0 < K; k0 += NSLAB * 32) {
#pragma unroll
        for (int s = 0; s < NSLAB; s++) {
#pragma unroll
            for (int it = 0; it < 2; it++) {
                int r = wave * 32 + it * 16;
                gload_lds16(A + (size_t)(bm + r + lrow) * K + k0 + s * 32 + lkc,
                            lA + s * 4096 + r * 32);
                gload_lds16(Bt + (size_t)(bn + r + lrow) * K + k0 + s * 32 + lkc,
                            lB + s * 4096 + r * 32);
            }
        }
        __syncthreads();
#pragma unroll
        for (int s = 0; s < NSLAB; s++) {
            short8 af[4], bfr[4];
#pragma unroll
            for (int mt = 0; mt < 4; mt++)
                af[mt] = *(const short8*)(lA + s * 4096 + (wm + mt * 16 + l16) * 32 + quad * 8);
#pragma unroll
            for (int nt = 0; nt < 4; nt++)
                bfr[nt] = *(const short8*)(lB + s * 4096 + (wn + nt * 16 + l16) * 32 + quad * 8);
#pragma unroll
            for (int mt = 0; mt < 4; mt++)
#pragma unroll
                for (int nt = 0; nt < 4; nt++)
                    acc[mt][nt] = __builtin_amdgcn_mfma_f32_16x16x32_bf16(af[mt], bfr[nt], acc[mt][nt], 0, 0, 0);
        }
        __syncthreads();
    }

    if constexpr (BF16OUT) {
        bf16* ltile = (bf16*)smem;
#pragma unroll
        for (int mt = 0; mt < 4; mt++) {
#pragma unroll
            for (int nt = 0; nt < 4; nt++) {
                int tc = wn + nt * 16 + l16;
#pragma unroll
                for (int r = 0; r < 4; r++) {
                    int tr = wm + mt * 16 + quad * 4 + r;
                    float v0 = acc[mt][nt][r];
                    if constexpr (BIAS) v0 += bias[bn + tc];
                    if constexpr (RELU) v0 = fmaxf(v0, 0.f);
                    ltile[tr * 136 + tc] = f2b(v0);
                }
            }
        }
        __syncthreads();
        bf16* C = (bf16*)Cv;
        int rr0 = tid >> 4, col8 = (tid & 15) * 8;
        int gc = bn + col8;
#pragma unroll
        for (int p = 0; p < 8; p++) {
            int rr = p * 16 + rr0;
            if (gc < N)
                *(short8*)(C + (size_t)(bm + rr) * N + gc) =
                    *(const short8*)(ltile + rr * 136 + col8);
        }
    } else {
        float* C = (float*)Cv;
#pragma unroll
        for (int mt = 0; mt < 4; mt++) {
#pragma unroll
            for (int nt = 0; nt < 4; nt++) {
                int gc = bn + wn + nt * 16 + l16;
                if (gc < N) {
#pragma unroll
                    for (int r = 0; r < 4; r++) {
                        int gr = bm + wm + mt * 16 + quad * 4 + r;
                        float v0 = acc[mt][nt][r];
                        if constexpr (BIAS) v0 += bias[gc];
                        if constexpr (RES) v0 += res[(size_t)gr * N + gc];
                        if constexpr (RELU) v0 = fmaxf(v0, 0.f);
                        C[(size_t)gr * N + gc] = v0;
                    }
                }
            }
        }
    }
}

// ---------------- 256x128-tile MFMA GEMM (FFN1 / FFN2): static N,K, BK=64 ----------------
// 4 waves, wave w owns rows w*64..w*64+63 x all 128 cols: acc 4x8, 12 b128 frag reads
// per 32 MFMA (LDS/MFMA = 0.375 vs 0.5 for 4x4 blocking). Requires M%256==0, K%64==0, N%128==0.
template <int N, int K, bool RELU, bool BIAS, bool RES, bool BF16OUT>
__global__ __launch_bounds__(256, 2) void gemm256_kernel(
    const bf16* __restrict__ A, const bf16* __restrict__ Bt,
    const float* __restrict__ bias, const float* __restrict__ res,
    void* __restrict__ Cv, int M)
{
    __shared__ __align__(16) char smem[49152];    // lA 2x256x32 (32KB) + lB 2x128x32 (16KB)
    bf16* lA = (bf16*)smem;
    bf16* lB = lA + 2 * 256 * 32;

    const int tid = threadIdx.x;
    const int bm = blockIdx.x * 256;
    const int bn = blockIdx.y * 128;
    const int wave = tid >> 6, lane = tid & 63;
    const int quad = lane >> 4, l16 = lane & 15;
    const int lrow = lane >> 2;
    const int lkc = (lane & 3) * 8;

    floatx4 acc[4][8] = {};

    for (int k0 = 0; k0 < K; k0 += 64) {
#pragma unroll
        for (int s = 0; s < 2; s++) {
#pragma unroll
            for (int it = 0; it < 4; it++) {       // A: 16 chunks of 16 rows, 4/wave
                int r = (wave * 4 + it) * 16;
                gload_lds16(A + (size_t)(bm + r + lrow) * K + k0 + s * 32 + lkc,
                            lA + s * 8192 + r * 32);
            }
#pragma unroll
            for (int it = 0; it < 2; it++) {       // B: 8 chunks of 16 rows, 2/wave
                int r = (wave * 2 + it) * 16;
                gload_lds16(Bt + (size_t)(bn + r + lrow) * K + k0 + s * 32 + lkc,
                            lB + s * 4096 + r * 32);
            }
        }
        __syncthreads();
#pragma unroll
        for (int s = 0; s < 2; s++) {
            short8 af[4], bfr[8];
#pragma unroll
            for (int mt = 0; mt < 4; mt++)
                af[mt] = *(const short8*)(lA + s * 8192 + (wave * 64 + mt * 16 + l16) * 32 + quad * 8);
#pragma unroll
            for (int nt = 0; nt < 8; nt++)
                bfr[nt] = *(const short8*)(lB + s * 4096 + (nt * 16 + l16) * 32 + quad * 8);
#pragma unroll
            for (int mt = 0; mt < 4; mt++)
#pragma unroll
                for (int nt = 0; nt < 8; nt++)
                    acc[mt][nt] = __builtin_amdgcn_mfma_f32_16x16x32_bf16(af[mt], bfr[nt], acc[mt][nt], 0, 0, 0);
        }
        __syncthreads();
    }

    // epilogue: 4 passes of 64 rows through LDS (bf16 stride 136 / fp32 stride 132)
    float bv[8];
    if constexpr (BIAS) {
#pragma unroll
        for (int nt = 0; nt < 8; nt++) bv[nt] = bias[bn + nt * 16 + l16];
    }
#pragma unroll
    for (int p = 0; p < 4; p++) {
        if (wave == p) {
            if constexpr (BF16OUT) {
                bf16* tile = (bf16*)smem;
#pragma unroll
                for (int mt = 0; mt < 4; mt++)
#pragma unroll
                    for (int nt = 0; nt < 8; nt++)
#pragma unroll
                        for (int r = 0; r < 4; r++) {
                            float v0 = acc[mt][nt][r];
                            if constexpr (BIAS) v0 += bv[nt];
                            if constexpr (RELU) v0 = fmaxf(v0, 0.f);
                            tile[(mt * 16 + quad * 4 + r) * 136 + nt * 16 + l16] = f2b(v0);
                        }
            } else {
                float* tile = (float*)smem;
#pragma unroll
                for (int mt = 0; mt < 4; mt++)
#pragma unroll
                    for (int nt = 0; nt < 8; nt++)
#pragma unroll
                        for (int r = 0; r < 4; r++) {
                            float v0 = acc[mt][nt][r];
                            if constexpr (BIAS) v0 += bv[nt];
                            if constexpr (RELU) v0 = fmaxf(v0, 0.f);
                            tile[(mt * 16 + quad * 4 + r) * 132 + nt * 16 + l16] = v0;
                        }
            }
        }
        __syncthreads();
        if constexpr (BF16OUT) {
            const bf16* tile = (const bf16*)smem;
            bf16* C = (bf16*)Cv;
            int col8 = (tid & 15) * 8, r0 = tid >> 4;
#pragma unroll
            for (int j = 0; j < 4; j++) {
                int rr = j * 16 + r0;
                *(short8*)(C + (size_t)(bm + p * 64 + rr) * N + bn + col8) =
                    *(const short8*)(tile + rr * 136 + col8);
            }
        } else {
            const float* tile = (const float*)smem;
            float* C = (float*)Cv;
            int col4 = (tid & 31) * 4, r0 = tid >> 5;
#pragma unroll
            for (int j = 0; j < 8; j++) {
                int rr = j * 8 + r0;
                float4 v = *(const float4*)(tile + rr * 132 + col4);
                size_t gi = (size_t)(bm + p * 64 + rr) * N + bn + col4;
                if constexpr (RES) {
                    float4 rv = *(const float4*)(res + gi);
                    v.x += rv.x; v.y += rv.y; v.z += rv.z; v.w += rv.w;
                }
                *(float4*)(C + gi) = v;
            }
        }
        __syncthreads();
    }
}

// ---------------- causal attention, online softmax; qkv layout [BT][216]: q|k|v each 72 cols ----------------
// 2 blocks per (b,h); wave->t-slab remap balances work: block0 slabs {0,2,5,7}, block1 {1,3,4,6}.
__global__ __launch_bounds__(256) void attn_kernel(const bf16* __restrict__ qkv, bf16* __restrict__ o_pad)
{
    int blk = blockIdx.x;
    int half = blk & 1;
    int bh = blk >> 1;
    int b = bh / NH, h = bh % NH;
    int wave = threadIdx.x >> 6, lane = threadIdx.x & 63;
    const int jmap0[4] = {0, 2, 5, 7}, jmap1[4] = {1, 3, 4, 6};
    int j = half ? jmap1[wave] : jmap0[wave];
    int t = j * 64 + lane;
    int smax = half ? 448 : 512;

    __shared__ float ks[512 * 6];
    __shared__ float vs[512 * 6];
    const bf16* base = qkv + (size_t)b * 512 * 216;
    for (int i = threadIdx.x; i < smax * 6; i += 256) {
        int s = i / 6, e = i % 6;
        ks[i] = b2f(base[s * 216 + 72 + h * 6 + e]);
        vs[i] = b2f(base[s * 216 + 144 + h * 6 + e]);
    }
    __syncthreads();

    float q0 = b2f(base[t * 216 + h * 6 + 0]);
    float q1 = b2f(base[t * 216 + h * 6 + 1]);
    float q2 = b2f(base[t * 216 + h * 6 + 2]);
    float q3 = b2f(base[t * 216 + h * 6 + 3]);
    float q4 = b2f(base[t * 216 + h * 6 + 4]);
    float q5 = b2f(base[t * 216 + h * 6 + 5]);

    const float scale = 0.4082482904638630f;  // 1/sqrt(6)
    float m = -1e30f, l = 0.f;
    float o0 = 0, o1 = 0, o2 = 0, o3 = 0, o4 = 0, o5 = 0;
    for (int s = 0; s <= t; s++) {
        const float* kk = &ks[s * 6];
        float sc = (q0 * kk[0] + q1 * kk[1] + q2 * kk[2] + q3 * kk[3] + q4 * kk[4] + q5 * kk[5]) * scale;
        float nm = fmaxf(m, sc);
        float alpha = __expf(m - nm);
        float p = __expf(sc - nm);
        l = l * alpha + p;
        const float* vv = &vs[s * 6];
        o0 = o0 * alpha + p * vv[0];
        o1 = o1 * alpha + p * vv[1];
        o2 = o2 * alpha + p * vv[2];
        o3 = o3 * alpha + p * vv[3];
        o4 = o4 * alpha + p * vv[4];
        o5 = o5 * alpha + p * vv[5];
        m = nm;
    }
    float inv = 1.f / l;
    bf16* orow = o_pad + (size_t)(b * 512 + t) * 96 + h * 6;
    orow[0] = f2b(o0 * inv);
    orow[1] = f2b(o1 * inv);
    orow[2] = f2b(o2 * inv);
    orow[3] = f2b(o3 * inv);
    orow[4] = f2b(o4 * inv);
    orow[5] = f2b(o5 * inv);
    // cols 72..95 of o_pad stay poison (finite bf16): matching wo_t k-cols are zero -> contributes 0.
}

extern "C" void kernel_launch(void* const* d_in, const int* in_sizes, int n_in,
                              void* d_out, int out_size, void* d_ws, size_t ws_size,
                              hipStream_t stream)
{
    const float* x   = (const float*)d_in[0];
    const float* Wq  = (const float*)d_in[1];
    const float* Wk  = (const float*)d_in[2];
    const float* Wv  = (const float*)d_in[3];
    const float* Wo  = (const float*)d_in[4];
    const float* bo  = (const float*)d_in[5];
    const float* W1  = (const float*)d_in[6];
    const float* b1  = (const float*)d_in[7];
    const float* W2  = (const float*)d_in[8];
    const float* b2  = (const float*)d_in[9];
    const float* g1  = (const float*)d_in[10];
    const float* be1 = (const float*)d_in[11];
    const float* g2  = (const float*)d_in[12];
    const float* be2 = (const float*)d_in[13];

    char* ws = (char*)d_ws;
    size_t off = 0;
    auto alloc = [&](size_t bytes) {
        void* p = ws + off;
        off = (off + bytes + 255) & ~(size_t)255;
        return p;
    };
    bf16*  xn    = (bf16*)alloc((size_t)BT * DIM * 2);   // LN output (reused for both LNs)
    bf16*  qkvb  = (bf16*)alloc((size_t)BT * 216 * 2);
    bf16*  o_pad = (bf16*)alloc((size_t)BT * 96 * 2);
    float* x1    = (float*)alloc((size_t)BT * DIM * 4);  // residual stream after attention, fp32
    bf16*  ffb   = (bf16*)alloc((size_t)BT * DFF * 2);
    bf16*  wqkv  = (bf16*)alloc((size_t)256 * 768 * 2);  // padded to 256 rows (zeros)
    bf16*  wo_t  = (bf16*)alloc((size_t)768 * 96 * 2);
    bf16*  w1t   = (bf16*)alloc((size_t)3072 * 768 * 2);
    bf16*  w2t   = (bf16*)alloc((size_t)768 * 3072 * 2);

    const int PACK_N = 256 * 768 + 768 * 96;
    pack_small_kernel<<<(PACK_N + 255) / 256, 256, 0, stream>>>(Wq, Wk, Wv, Wo, wqkv, wo_t);
    transpose_kernel<<<dim3(3072 / 32, 768 / 32), 256, 0, stream>>>(W1, w1t, 768, 3072);
    transpose_kernel<<<dim3(768 / 32, 3072 / 32), 256, 0, stream>>>(W2, w2t, 3072, 768);

    ln_kernel<<<BT, 192, 0, stream>>>(x, g1, be1, xn);
    gemm_kernel<216, 768, 2, false, false, false, true><<<dim3(128, 2), 256, 0, stream>>>(
        xn, wqkv, nullptr, nullptr, qkvb, BT);
    attn_kernel<<<32 * NH * 2, 256, 0, stream>>>(qkvb, o_pad);
    gemm_kernel<768, 96, 1, false, true, true, false><<<dim3(128, 6), 256, 0, stream>>>(
        o_pad, wo_t, bo, x, x1, BT);
    ln_kernel<<<BT, 192, 0, stream>>>(x1, g2, be2, xn);
    gemm256_kernel<3072, 768, true, true, false, true><<<dim3(64, 24), 256, 0, stream>>>(
        xn, w1t, b1, nullptr, ffb, BT);
    gemm256_kernel<768, 3072, false, true, true, false><<<dim3(64, 6), 256, 0, stream>>>(
        ffb, w2t, b2, x1, (float*)d_out, BT);
}